// Round 16
// baseline (713.661 us; speedup 1.0000x reference)
//
#include <hip/hip_runtime.h>
#include <cstdint>

typedef short short8 __attribute__((ext_vector_type(8)));
typedef float f32x4 __attribute__((ext_vector_type(4)));
typedef int   i32x4 __attribute__((ext_vector_type(4)));
typedef uint32_t u32x4 __attribute__((ext_vector_type(4)));
typedef unsigned short u16;
typedef signed char i8;
typedef unsigned long long u64;

// ---------------- helpers ----------------
__device__ __forceinline__ u16 f2bf(float f) {
  union { float f; uint32_t u; } v; v.f = f;
  uint32_t u = v.u;
  uint32_t r = (u + 0x7fffu + ((u >> 16) & 1u)) >> 16;
  return (u16)r;
}
__device__ __forceinline__ float bf2f(u16 b) {
  union { uint32_t u; float f; } v; v.u = ((uint32_t)b) << 16; return v.f;
}
__device__ __forceinline__ i8 q8(float v, float s) {
  float x = rintf(v * s);
  x = fminf(fmaxf(x, -127.f), 127.f);
  return (i8)(int)x;
}
__device__ __forceinline__ float sigm(float x) { return 1.f / (1.f + expf(-x)); }
__device__ __forceinline__ float tanh_f(float x) { return 2.f / (1.f + expf(-2.f * x)) - 1.f; }

typedef const __attribute__((address_space(1))) uint32_t glb_u32;
typedef __attribute__((address_space(3))) uint32_t lds_u32;
__device__ __forceinline__ void glds16(const void* g, void* l) {
  __builtin_amdgcn_global_load_lds((glb_u32*)g, (lds_u32*)l, 16, 0, 0);
}

__device__ __forceinline__ void tfround(uint32_t& a, uint32_t& b, int r) {
  a += b; b = (b << r) | (b >> (32 - r)); b ^= a;
}
// exact JAX threefry2x32 (key 42 -> k0=0,k1=42)
__device__ __forceinline__ void threefry(uint32_t k0, uint32_t k1, uint32_t& x0, uint32_t& x1) {
  uint32_t k2 = k0 ^ k1 ^ 0x1BD11BDAu;
  x0 += k0; x1 += k1;
  tfround(x0,x1,13); tfround(x0,x1,15); tfround(x0,x1,26); tfround(x0,x1,6);
  x0 += k1; x1 += k2 + 1u;
  tfround(x0,x1,17); tfround(x0,x1,29); tfround(x0,x1,16); tfround(x0,x1,24);
  x0 += k2; x1 += k0 + 2u;
  tfround(x0,x1,13); tfround(x0,x1,15); tfround(x0,x1,26); tfround(x0,x1,6);
  x0 += k0; x1 += k1 + 3u;
  tfround(x0,x1,17); tfround(x0,x1,29); tfround(x0,x1,16); tfround(x0,x1,24);
  x0 += k1; x1 += k2 + 4u;
  tfround(x0,x1,13); tfround(x0,x1,15); tfround(x0,x1,26); tfround(x0,x1,6);
  x0 += k2; x1 += k0 + 5u;
}
__device__ __forceinline__ float gumbel_from_bits(uint32_t bits) {
  float f = __uint_as_float((bits >> 9) | 0x3f800000u) - 1.0f;
  const float tiny = 1.17549435e-38f;
  float u = fmaxf(f + tiny, tiny);
  return -logf(-logf(u));
}

// ---------------- prep: pack/convert weights (8-wide vectorized) ----------------
// Packed row index for Wih/bsum/xg columns: p = u*4 + g (gate-interleaved).
// e2v packed as int8, scale 400.
__global__ __launch_bounds__(256) void prep_all(
    const float* eWih, const float* eWhh, const float* ebih, const float* ebhh,
    const float* dWih, const float* dWhh, const float* dbih, const float* dbhh,
    const float* h2e_w, const float* h2e_b, const float* e2v_w,
    u16* wih_p, u16* whh_p, float* bsum, u16* h2e_p, float* h2e_bp,
    i8* e2v_q, u16* hglob, int* bar)
{
  const uint32_t GWIH = 2u*2048u*40u;      // 163840  (groups of 8 along k, 320/8)
  const uint32_t GWHH = 2u*2048u*64u;      // 262144
  const uint32_t GBS  = 512u;              // 2*2048/8
  const uint32_t GH2E = 512u*128u;         // 65536
  const uint32_t GH2EB= 64u;
  const uint32_t GE2V = 32000u*64u;        // 2048000
  const uint32_t GHG  = 16384u;            // 2*2*64*512/8
  const uint32_t GBAR = 512u;              // flag region (2 lstm x 256 ints)
  const uint32_t TOT  = GWIH+GWHH+GBS+GH2E+GH2EB+GE2V+GHG+GBAR;
  for (uint32_t i = blockIdx.x*256u + threadIdx.x; i < TOT; i += gridDim.x*256u) {
    uint32_t j = i;
    if (j < GWIH) { // [L][2048][320]: row p = u*4+g <- Wih[g*500+u][k0..k0+8]
      uint32_t L = j / (2048u*40u), rem = j % (2048u*40u);
      uint32_t p = rem / 40u, kg = rem % 40u;
      uint32_t u = p >> 2, g = p & 3u, k0 = kg*8u;
      short8 o = {0,0,0,0,0,0,0,0}; u16* op = (u16*)&o;
      if (u < 500u) {
        const float* src = (L ? dWih : eWih) + ((size_t)(g*500u+u))*300u + k0;
        if (k0 + 8u <= 300u) {
          float4 a = *(const float4*)src, b = *(const float4*)(src+4);
          op[0]=f2bf(a.x);op[1]=f2bf(a.y);op[2]=f2bf(a.z);op[3]=f2bf(a.w);
          op[4]=f2bf(b.x);op[5]=f2bf(b.y);op[6]=f2bf(b.z);op[7]=f2bf(b.w);
        } else {
          #pragma unroll
          for (int e = 0; e < 8; ++e) if (k0+e < 300u) op[e] = f2bf(src[e]);
        }
      }
      *(short8*)(wih_p + (size_t)j*8) = o; continue;
    }
    j -= GWIH;
    if (j < GWHH) { // [L][row][512], row = wg*128 + gate*32 + ul (16 wgs x 4 gate-waves)
      uint32_t L = j / (2048u*64u), rem = j % (2048u*64u);
      uint32_t row = rem >> 6, kg = rem & 63u, k0 = kg*8u;
      uint32_t wg = row >> 7, r2 = row & 127u, g = r2 >> 5, ul = r2 & 31u;
      uint32_t u = wg*32u + ul;
      short8 o = {0,0,0,0,0,0,0,0}; u16* op = (u16*)&o;
      if (u < 500u) {
        const float* src = (L ? dWhh : eWhh) + ((size_t)(g*500u+u))*500u + k0;
        if (k0 + 8u <= 500u) {
          float4 a = *(const float4*)src, b = *(const float4*)(src+4);
          op[0]=f2bf(a.x);op[1]=f2bf(a.y);op[2]=f2bf(a.z);op[3]=f2bf(a.w);
          op[4]=f2bf(b.x);op[5]=f2bf(b.y);op[6]=f2bf(b.z);op[7]=f2bf(b.w);
        } else {
          #pragma unroll
          for (int e = 0; e < 8; ++e) if (k0+e < 500u) op[e] = f2bf(src[e]);
        }
      }
      *(short8*)(whh_p + (size_t)j*8) = o; continue;
    }
    j -= GWHH;
    if (j < GBS) { // [L][2048] fp32, p = u*4+g
      uint32_t L = j >> 8, pg = j & 255u, p0 = pg*8u;
      float arr[8];
      #pragma unroll
      for (int e = 0; e < 8; ++e) {
        uint32_t p = p0 + e, u = p >> 2, g = p & 3u;
        arr[e] = (u < 500u) ? ((L?dbih:ebih)[g*500u+u] + (L?dbhh:ebhh)[g*500u+u]) : 0.f;
      }
      *(float4*)(bsum + (size_t)j*8) = *(float4*)arr;
      *(float4*)(bsum + (size_t)j*8 + 4) = *(float4*)(arr+4);
      continue;
    }
    j -= GBS;
    if (j < GH2E) { // [512][1024]: k<500 -> k ; 512..1011 -> k-12
      uint32_t n = j >> 7, kg = j & 127u, k0 = kg*8u;
      short8 o = {0,0,0,0,0,0,0,0}; u16* op = (u16*)&o;
      if (n < 500u) {
        const float* rowp = h2e_w + (size_t)n*1000u;
        if (k0 + 8u <= 500u) {
          float4 a = *(const float4*)(rowp+k0), b = *(const float4*)(rowp+k0+4);
          op[0]=f2bf(a.x);op[1]=f2bf(a.y);op[2]=f2bf(a.z);op[3]=f2bf(a.w);
          op[4]=f2bf(b.x);op[5]=f2bf(b.y);op[6]=f2bf(b.z);op[7]=f2bf(b.w);
        } else if (k0 >= 512u && k0 + 8u <= 1012u) {
          #pragma unroll
          for (int e = 0; e < 8; ++e) op[e] = f2bf(rowp[k0 + e - 12u]);
        } else {
          #pragma unroll
          for (int e = 0; e < 8; ++e) {
            uint32_t k = k0 + e; float v = 0.f;
            if (k < 500u) v = rowp[k];
            else if (k >= 512u && k < 1012u) v = rowp[k - 12u];
            op[e] = f2bf(v);
          }
        }
      }
      *(short8*)(h2e_p + (size_t)j*8) = o; continue;
    }
    j -= GH2E;
    if (j < GH2EB) {
      uint32_t k0 = j*8u;
      float arr[8];
      #pragma unroll
      for (int e = 0; e < 8; ++e) { uint32_t k = k0+e; arr[e] = (k < 500u) ? h2e_b[k] : 0.f; }
      *(float4*)(h2e_bp + (size_t)j*8) = *(float4*)arr;
      *(float4*)(h2e_bp + (size_t)j*8 + 4) = *(float4*)(arr+4);
      continue;
    }
    j -= GH2EB;
    if (j < GE2V) { // [32000][512] int8, w_q = rint(w*400)
      uint32_t n = j >> 6, kg = j & 63u, k0 = kg*8u;
      i8 o[8] = {0,0,0,0,0,0,0,0};
      const float* src = e2v_w + (size_t)n*500u + k0;
      if (k0 + 8u <= 500u) {
        float4 a = *(const float4*)src, b = *(const float4*)(src+4);
        o[0]=q8(a.x,400.f);o[1]=q8(a.y,400.f);o[2]=q8(a.z,400.f);o[3]=q8(a.w,400.f);
        o[4]=q8(b.x,400.f);o[5]=q8(b.y,400.f);o[6]=q8(b.z,400.f);o[7]=q8(b.w,400.f);
      } else {
        #pragma unroll
        for (int e = 0; e < 8; ++e) if (k0+e < 500u) o[e] = q8(src[e], 400.f);
      }
      *(u64*)(e2v_q + (size_t)j*8) = *(const u64*)o; continue;
    }
    j -= GE2V;
    if (j < GHG) { short8 z = {0,0,0,0,0,0,0,0}; *(short8*)(hglob + (size_t)j*8) = z; continue; }
    j -= GHG;
    if (j < GBAR) bar[j] = 0;
  }
}

// ---------------- fused dual-LSTM, 32 wgs x 256 thr, flag-vector barrier -------------
__global__ __launch_bounds__(256, 1) void lstm_kernel(
    const u16* xg /*[2][3200][2048] bf16 gate-interleaved (bias pre-added)*/, const u16* whh_p,
    u16* hglob /*[2buf][2lstm][64][512]*/, float* h_out /*[2][64][50][512]*/, int* bar)
{
  const int wg = blockIdx.x;     // 0..31
  const int lstm = wg >> 4;
  const int wgl = wg & 15;       // unit block (32 units)
  const int tid = threadIdx.x;
  const int wid = tid >> 6;      // wave = gate (i,f,g,o)
  const int lane = tid & 63;

  __shared__ u16 hbuf[64 * 512];        // 64KB, XOR-swizzled rows
  __shared__ float pre[4][64][34];      // stride 34 (==2 mod 8): 2-way max = free
  __shared__ u16 hsh[64 * 32];          // 4KB h-slice repack for 16B coherent stores

  // Whh fragments resident in registers: wave's 32 gate-rows x K=512
  short8 wf[2][16];
  {
    const u16* wbase = whh_p + ((size_t)lstm*2048 + wgl*128 + wid*32) * 512;
    #pragma unroll
    for (int nt = 0; nt < 2; ++nt)
      #pragma unroll
      for (int kk = 0; kk < 16; ++kk) {
        int row = nt*16 + (lane & 15);
        int k = kk*32 + (lane >> 4)*8;
        wf[nt][kk] = *(const short8*)(wbase + (size_t)row*512 + k);
      }
  }

  float c[8];
  #pragma unroll
  for (int q = 0; q < 8; ++q) c[q] = 0.f;

  int* flags = bar + lstm*256;      // 16 flags, 64B apart
  const int ug = wgl*32 + (tid & 31);
  const u16* xgl = xg + ((size_t)lstm*3200)*2048;

  // prefetch xg for t=0: one 8B load per batch (4 gates of unit ug, interleaved layout)
  float xr[4][8];
  #pragma unroll
  for (int q = 0; q < 8; ++q) {
    int b = q*8 + (tid >> 5);
    u64 w = *(const u64*)(xgl + ((size_t)(b*50 + 0))*2048 + ug*4);
    #pragma unroll
    for (int g = 0; g < 4; ++g) xr[g][q] = bf2f((u16)(w >> (g*16)));
  }

  #pragma unroll 1
  for (int t = 0; t < 50; ++t) {
    const int cur = t & 1;
    // ---- stage h[64][512]: 16 pipelined device-scope 16B loads -> swizzled LDS ----
    {
      u32x4 sv[16];
      const char* sbase = (const char*)(hglob + ((size_t)(cur*2 + lstm))*64*512);
      #pragma unroll
      for (int i = 0; i < 16; ++i) {
        const void* p = sbase + (size_t)(i*256 + tid)*16;
        asm volatile("global_load_dwordx4 %0, %1, off sc0 sc1" : "=v"(sv[i]) : "v"(p));
      }
      asm volatile("s_waitcnt vmcnt(0)" ::: "memory");
      __builtin_amdgcn_sched_barrier(0);
      #pragma unroll
      for (int i = 0; i < 16; ++i) {
        int chunk = i*256 + tid;               // 16B chunks, 64 per 1024B row
        int row = chunk >> 6, col16 = chunk & 63;
        int byte = row*1024 + ((col16*16) ^ ((row & 7) << 4));
        *(u32x4*)((char*)hbuf + byte) = sv[i];
      }
    }
    __syncthreads();

    // ---- MFMA: pre = h @ Whh_slice^T ----
    f32x4 zero = {0.f, 0.f, 0.f, 0.f};
    f32x4 acc[4][2];
    #pragma unroll
    for (int m = 0; m < 4; ++m) { acc[m][0] = zero; acc[m][1] = zero; }

    #pragma unroll
    for (int kk = 0; kk < 16; ++kk) {
      short8 af[4];
      #pragma unroll
      for (int m = 0; m < 4; ++m) {
        int row = m*16 + (lane & 15);
        int byte = row*1024 + ((kk*64 + (lane >> 4)*16) ^ ((row & 7) << 4));
        af[m] = *(const short8*)((const char*)hbuf + byte);
      }
      #pragma unroll
      for (int m = 0; m < 4; ++m) {
        acc[m][0] = __builtin_amdgcn_mfma_f32_16x16x32_bf16(af[m], wf[0][kk], acc[m][0], 0, 0, 0);
        acc[m][1] = __builtin_amdgcn_mfma_f32_16x16x32_bf16(af[m], wf[1][kk], acc[m][1], 0, 0, 0);
      }
    }

    #pragma unroll
    for (int m = 0; m < 4; ++m)
      #pragma unroll
      for (int nt = 0; nt < 2; ++nt)
        #pragma unroll
        for (int jj = 0; jj < 4; ++jj) {
          int row = m*16 + (lane >> 4)*4 + jj;   // batch
          int col = nt*16 + (lane & 15);         // unit local
          pre[wid][row][col] = acc[m][nt][jj];
        }
    __syncthreads();

    // ---- gates epilogue (xg in registers); h_out deferred off the critical path ----
    float hq[8];
    #pragma unroll
    for (int q = 0; q < 8; ++q) {
      int b = q*8 + (tid >> 5);
      int ul = tid & 31;
      float pi = pre[0][b][ul] + xr[0][q];
      float pf = pre[1][b][ul] + xr[1][q];
      float pg = pre[2][b][ul] + xr[2][q];
      float po = pre[3][b][ul] + xr[3][q];
      c[q] = sigm(pf)*c[q] + sigm(pi)*tanh_f(pg);
      float h = sigm(po)*tanh_f(c[q]);
      if (ug >= 500) h = 0.f;
      hq[q] = h;
      hsh[b*32 + ul] = f2bf(h);
    }
    if (t == 49) {
      #pragma unroll
      for (int q = 0; q < 8; ++q) {
        int b = q*8 + (tid >> 5);
        h_out[(((size_t)(lstm*64 + b))*50 + t)*512 + ug] = hq[q];
      }
      break;                          // no exchange needed after last step
    }
    __syncthreads();   // hsh complete

    // ---- cooperative device-scope store of this wg's h slice (16B/thread) ----
    {
      u16* hdst = hglob + ((size_t)((cur^1)*2 + lstm))*64*512;
      int b2 = tid >> 2, c8 = (tid & 3)*8;
      u32x4 w = *(const u32x4*)(hsh + b2*32 + c8);
      void* dp = hdst + (size_t)b2*512 + wgl*32 + c8;
      asm volatile("global_store_dwordx4 %0, %1, off sc0 sc1" :: "v"(dp), "v"(w) : "memory");
    }
    asm volatile("s_waitcnt vmcnt(0)" ::: "memory");   // drains ONLY hglob stores now
    __syncthreads();                                   // ALL waves drained

    if (tid == 0)
      __hip_atomic_store(flags + wgl*16, t+1, __ATOMIC_RELAXED, __HIP_MEMORY_SCOPE_AGENT);

    // overlap region (flies under the flag poll): h_out writes + xg prefetch
    #pragma unroll
    for (int q = 0; q < 8; ++q) {
      int b = q*8 + (tid >> 5);
      h_out[(((size_t)(lstm*64 + b))*50 + t)*512 + ug] = hq[q];
    }
    {
      const int tn = t + 1;
      #pragma unroll
      for (int q = 0; q < 8; ++q) {
        int b = q*8 + (tid >> 5);
        u64 w = *(const u64*)(xgl + ((size_t)(b*50 + tn))*2048 + ug*4);
        #pragma unroll
        for (int g = 0; g < 4; ++g) xr[g][q] = bf2f((u16)(w >> (g*16)));
      }
    }

    // ---- flag-vector poll: wave 0, lane j watches flag j (4x coverage) ----
    if (wid == 0) {
      int fj = (lane & 15) * 16;
      while (true) {
        int v = __hip_atomic_load(flags + fj, __ATOMIC_RELAXED, __HIP_MEMORY_SCOPE_AGENT);
        if (__ballot(v >= t + 1) == ~0ull) break;
      }
    }
    __syncthreads();
  }
}

// -------- scores+sample fused: per-b enc staged in LDS, inline exact sampling --------
__global__ __launch_bounds__(256) void scores_sample_kernel(const float* h_out,
                                                            int* samples, float* logp_s) {
  int b = blockIdx.x >> 2, tq = blockIdx.x & 3;
  int tid = threadIdx.x, wid = tid >> 6, lane = tid & 63;
  __shared__ float enc[50*512];   // 100KB
  const float* ebase = h_out + ((size_t)b*50)*512;
  for (int i = tid*4; i < 50*512; i += 256*4)
    *(float4*)(enc + i) = *(const float4*)(ebase + i);
  __syncthreads();
  const int t0 = tq*13;
  const int cnt = (tq == 3) ? 10 : 13;
  for (int tl = wid; tl < cnt; tl += 4) {
    int t = t0 + tl;
    const float* drow = h_out + ((size_t)((64 + b)*50 + t))*512;
    float d[8];
    #pragma unroll
    for (int j = 0; j < 8; ++j) d[j] = drow[lane + j*64];
    float sc = -INFINITY;
    for (int s = 0; s < 50; ++s) {
      float p = 0.f;
      #pragma unroll
      for (int j = 0; j < 8; ++j) p += enc[s*512 + lane + j*64] * d[j];
      #pragma unroll
      for (int mk = 32; mk; mk >>= 1) p += __shfl_xor(p, mk);
      if (lane == s) sc = p;            // full-reduced value lives on every lane
    }
    // ---- inline exact jax.random.categorical(key(42)) on this wave ----
    const int pidx = b*49 + t;
    float val = -INFINITY;
    if (lane < 50) {
      uint32_t i = (uint32_t)(pidx*50 + lane);
      uint32_t x0, x1; int sel;
      if (i < 78400u) { x0 = i; x1 = i + 78400u; sel = 0; }
      else            { x0 = i - 78400u; x1 = i; sel = 1; }
      threefry(0u, 42u, x0, x1);
      val = sc + gumbel_from_bits(sel ? x1 : x0);
    }
    int idx = lane; float v = val;
    #pragma unroll
    for (int mk = 1; mk < 64; mk <<= 1) {
      float ov = __shfl_xor(v, mk);
      int oi = __shfl_xor(idx, mk);
      if (ov > v || (ov == v && oi < idx)) { v = ov; idx = oi; }
    }
    float m = sc;
    #pragma unroll
    for (int mk = 1; mk < 64; mk <<= 1) m = fmaxf(m, __shfl_xor(m, mk));
    float e = (lane < 50) ? expf(sc - m) : 0.f;
    #pragma unroll
    for (int mk = 1; mk < 64; mk <<= 1) e += __shfl_xor(e, mk);
    float lse = m + logf(e);
    float scs = __shfl(sc, idx);
    if (lane == 0) { samples[pidx] = idx; logp_s[pidx] = scs - lse; }
  }
}

// ---------------- generic 128x128x64 MFMA GEMM (reg-staged A/B) ----------
// AMODE: 0 emb-gather(fp32->bf16), 1 feat-gather(fp32->bf16)
// EPI:   0 bf16 store + bias (xg, ldc 2048, z-offset), 1 tanh(acc+bias)->int8 (ldc 512)
template <int AMODE, int EPI>
__global__ __launch_bounds__(256) void gemm_k(
    const float* Af32a, const float* Af32b, const int* gia, const int* gib,
    const u16* Bp, int ldkB, int KT,
    u16* Cbf, const float* bias)
{
  const int Mb = blockIdx.x, Nb = blockIdx.y, zb = blockIdx.z;
  const int tid = threadIdx.x;
  const int wid = tid >> 6, lane = tid & 63;
  const int wr = wid >> 1, wc = wid & 1;

  __shared__ u16 As[2*128*64];
  __shared__ u16 Bs[2*128*64];

  f32x4 zero = {0.f,0.f,0.f,0.f};
  f32x4 acc[4][4];
  #pragma unroll
  for (int m = 0; m < 4; ++m)
    #pragma unroll
    for (int n = 0; n < 4; ++n) acc[m][n] = zero;

  auto MFMA_STEP = [&](int buf) {
    #pragma unroll
    for (int kk2 = 0; kk2 < 2; ++kk2) {
      short8 a[4], b[4];
      #pragma unroll
      for (int m = 0; m < 4; ++m) {
        int row = wr*64 + m*16 + (lane & 15);
        int byte = buf*16384 + row*128 + ((kk2*64 + (lane >> 4)*16) ^ ((row & 7) << 4));
        a[m] = *(const short8*)((const char*)As + byte);
      }
      #pragma unroll
      for (int n = 0; n < 4; ++n) {
        int row = wc*64 + n*16 + (lane & 15);
        int byte = buf*16384 + row*128 + ((kk2*64 + (lane >> 4)*16) ^ ((row & 7) << 4));
        b[n] = *(const short8*)((const char*)Bs + byte);
      }
      #pragma unroll
      for (int m = 0; m < 4; ++m)
        #pragma unroll
        for (int n = 0; n < 4; ++n)
          acc[m][n] = __builtin_amdgcn_mfma_f32_16x16x32_bf16(a[m], b[n], acc[m][n], 0, 0, 0);
    }
  };

  const int r = tid >> 1;
  const int koff = (tid & 1)*32;
  const int growA = Mb*128 + r;
  const int growB = Nb*128 + r;

  const float* emb = nullptr; const int* ids = nullptr;
  int fb = 0, ft = 0, fsmp = 0; bool fvalid = true;
  if constexpr (AMODE == 0) {
    emb = zb ? Af32b : Af32a;
    ids = zb ? gib : gia;
  } else {
    fvalid = growA < 3136;
    fb = growA / 49; ft = growA - fb*49;
    fsmp = fvalid ? gia[growA] : 0;
  }

  short8 av8[4], bv8[4];
  auto FETCH = [&](int it) {
    const int k0 = it*64 + koff;
    u16* avp = (u16*)av8;
    if constexpr (AMODE == 0) {
      const float* srow = emb + (size_t)ids[growA]*300;
      #pragma unroll
      for (int j = 0; j < 8; ++j) {
        int k = k0 + j*4;
        float4 v = make_float4(0.f,0.f,0.f,0.f);
        if (k + 4 <= 300) v = *(const float4*)(srow + k);
        avp[j*4+0]=f2bf(v.x); avp[j*4+1]=f2bf(v.y); avp[j*4+2]=f2bf(v.z); avp[j*4+3]=f2bf(v.w);
      }
    } else {
      #pragma unroll
      for (int j = 0; j < 8; ++j) {
        int k = k0 + j*4;
        float4 v = make_float4(0.f,0.f,0.f,0.f);
        if (fvalid) {
          if (k + 4 <= 500) v = *(const float4*)(Af32a + ((size_t)(fb*50 + ft))*512 + k);
          else if (k >= 512 && k + 4 <= 1012) v = *(const float4*)(Af32b + ((size_t)(fb*50 + fsmp))*512 + (k - 512));
        }
        avp[j*4+0]=f2bf(v.x); avp[j*4+1]=f2bf(v.y); avp[j*4+2]=f2bf(v.z); avp[j*4+3]=f2bf(v.w);
      }
    }
    #pragma unroll
    for (int j = 0; j < 4; ++j)
      bv8[j] = *(const short8*)(Bp + (size_t)growB*ldkB + k0 + j*8);
  };
  auto STORE_LDS = [&](int buf) {
    #pragma unroll
    for (int j = 0; j < 4; ++j) {
      int byte = buf*16384 + r*128 + ((koff*2 + j*16) ^ ((r & 7) << 4));
      *(short8*)((char*)As + byte) = av8[j];
      *(short8*)((char*)Bs + byte) = bv8[j];
    }
  };

  FETCH(0);
  STORE_LDS(0);
  __syncthreads();
  for (int it = 0; it < KT; ++it) {
    const int cur = it & 1;
    if (it + 1 < KT) FETCH(it + 1);
    MFMA_STEP(cur);
    __syncthreads();
    if (it + 1 < KT) {
      STORE_LDS(cur ^ 1);
      __syncthreads();
    }
  }

  if constexpr (EPI == 0) {
    u16* C = Cbf + (size_t)zb*3200*2048;
    const float* bs = bias + (size_t)zb*2048;
    #pragma unroll
    for (int m = 0; m < 4; ++m)
      #pragma unroll
      for (int n = 0; n < 4; ++n)
        #pragma unroll
        for (int jj = 0; jj < 4; ++jj) {
          int row = Mb*128 + wr*64 + m*16 + (lane >> 4)*4 + jj;
          int col = Nb*128 + wc*64 + n*16 + (lane & 15);
          C[(size_t)row*2048 + col] = f2bf(acc[m][n][jj] + bs[col]);
        }
  } else {
    i8* Cq = (i8*)Cbf;
    #pragma unroll
    for (int m = 0; m < 4; ++m)
      #pragma unroll
      for (int n = 0; n < 4; ++n)
        #pragma unroll
        for (int jj = 0; jj < 4; ++jj) {
          int row = Mb*128 + wr*64 + m*16 + (lane >> 4)*4 + jj;
          int col = Nb*128 + wc*64 + n*16 + (lane & 15);
          float e = tanh_f(acc[m][n][jj] + bias[col]);
          Cq[(size_t)row*512 + col] = q8(e, 127.f);
        }
  }
}

// ------- e2v int8 GEMM: 128x128, K=512 via 8 x mfma_i32_16x16x64_i8 ------------------
// A read directly from global (L2-resident) into registers; B via glds double-buffer.
// LDS 18KB -> 4 wgs/CU. logits = (e_q . w_q)/(127*400) + bias; fused LSE partials.
__global__ __launch_bounds__(256) void gemm_e2v_i8(
    const i8* e_q /*[3200][512]*/, const i8* w_q /*[32000][512]*/,
    const int* x_en, const float* bias,
    float* pm, float* ps, float* ylogit)
{
  int bid = blockIdx.y*gridDim.x + blockIdx.x;
  const int NBLK = 25*250, q = NBLK/8, r = NBLK%8;   // 781, 2
  int xcd = bid & 7, idx = bid >> 3;
  int wgid = (xcd < r ? xcd*(q+1) : r*(q+1) + (xcd-r)*q) + idx;
  int Mb = wgid % 25, Nb = wgid / 25;
  const int tid = threadIdx.x;
  const int wid = tid >> 6, lane = tid & 63;
  const int wr = wid >> 1, wc = wid & 1;

  __shared__ i8 Bs[2*128*64];       // 2 x 8KB (64B rows = K=64 i8)
  __shared__ float part[128][2][2];

  i32x4 acc[4][4];
  #pragma unroll
  for (int m = 0; m < 4; ++m)
    #pragma unroll
    for (int n = 0; n < 4; ++n) { i32x4 z = {0,0,0,0}; acc[m][n] = z; }

  // per-lane A base: rows Mb*128 + wr*64 + m*16 + (lane&15), col chunk (lane>>4)*16
  const i8* abase = e_q + (size_t)(Mb*128 + wr*64 + (lane & 15))*512 + (lane >> 4)*16;

  auto ISSUE_B = [&](int it, int buf) {
    #pragma unroll
    for (int i = 0; i < 2; ++i) {
      int chunk = i*256 + tid;        // 512 chunks/tile, 4 x 16B per 64B row
      int row = chunk >> 2, c = chunk & 3;
      int cg = c ^ ((row >> 1) & 3);  // source pre-swizzle == read swizzle
      const i8* sb = w_q + (size_t)(Nb*128 + row)*512 + it*64 + cg*16;
      char* db = (char*)Bs + buf*8192 + i*4096 + wid*1024;   // wave-uniform base
      glds16(sb, db);
    }
  };

  auto MFMA_STEP = [&](int it, int buf) {
    i32x4 a[4], b[4];
    #pragma unroll
    for (int m = 0; m < 4; ++m)
      a[m] = *(const i32x4*)(abase + (size_t)m*16*512 + it*64);   // direct from L2
    #pragma unroll
    for (int n = 0; n < 4; ++n) {
      int row = wc*64 + n*16 + (lane & 15);
      int byte = buf*8192 + row*64 + (((lane >> 4)*16) ^ (((row >> 1) & 3) << 4));
      b[n] = *(const i32x4*)((const char*)Bs + byte);
    }
    #pragma unroll
    for (int m = 0; m < 4; ++m)
      #pragma unroll
      for (int n = 0; n < 4; ++n)
        acc[m][n] = __builtin_amdgcn_mfma_i32_16x16x64_i8(a[m], b[n], acc[m][n], 0, 0, 0);
  };

  ISSUE_B(0, 0);
  asm volatile("s_waitcnt vmcnt(0)" ::: "memory");
  __syncthreads();
  for (int it = 0; it < 8; ++it) {
    const int buf = it & 1;
    if (it + 1 < 8) ISSUE_B(it + 1, buf ^ 1);   // B loads fly under A-loads + MFMA
    MFMA_STEP(it, buf);
    if (it + 1 < 8) {
      asm volatile("s_waitcnt vmcnt(0)" ::: "memory");
      __syncthreads();
    }
  }

  const float DEQ = 1.f / (127.f * 400.f);
  float bias4[4];
  #pragma unroll
  for (int n = 0; n < 4; ++n) bias4[n] = bias[Nb*128 + wc*64 + n*16 + (lane & 15)];
  #pragma unroll
  for (int m = 0; m < 4; ++m)
    #pragma unroll
    for (int jj = 0; jj < 4; ++jj) {
      int trow = wr*64 + m*16 + (lane >> 4)*4 + jj;
      int grow = Mb*128 + trow;
      float x0 = (float)acc[m][0][jj]*DEQ + bias4[0];
      float x1 = (float)acc[m][1][jj]*DEQ + bias4[1];
      float x2 = (float)acc[m][2][jj]*DEQ + bias4[2];
      float x3 = (float)acc[m][3][jj]*DEQ + bias4[3];
      float mx = fmaxf(fmaxf(x0,x1), fmaxf(x2,x3));
      #pragma unroll
      for (int mk = 1; mk < 16; mk <<= 1) mx = fmaxf(mx, __shfl_xor(mx, mk));
      float sm = expf(x0-mx) + expf(x1-mx) + expf(x2-mx) + expf(x3-mx);
      #pragma unroll
      for (int mk = 1; mk < 16; mk <<= 1) sm += __shfl_xor(sm, mk);
      if (grow < 3136) {
        int b = grow / 49, tt = grow - b*49;
        int yv = x_en[b*50 + tt + 1];
        int cb = yv - (Nb*128 + wc*64);
        if (cb == 0*16 + (lane & 15)) ylogit[grow] = x0;
        if (cb == 1*16 + (lane & 15)) ylogit[grow] = x1;
        if (cb == 2*16 + (lane & 15)) ylogit[grow] = x2;
        if (cb == 3*16 + (lane & 15)) ylogit[grow] = x3;
      }
      if ((lane & 15) == 0) { part[trow][wc][0] = mx; part[trow][wc][1] = sm; }
    }
  __syncthreads();
  if (tid < 128) {
    int grow = Mb*128 + tid;
    if (grow < 3136) {
      float m0 = part[tid][0][0], s0 = part[tid][0][1];
      float m1 = part[tid][1][0], s1 = part[tid][1][1];
      float M = fmaxf(m0, m1);
      float S = s0*expf(m0 - M) + s1*expf(m1 - M);
      pm[(size_t)grow*250 + Nb] = M;
      ps[(size_t)grow*250 + Nb] = S;
    }
  }
}

// ---------------- combine LSE partials -> reward (wave-parallel) ----------------
__global__ __launch_bounds__(256) void lse_reduce(const float* pm, const float* ps,
                                                  const float* ylogit, float* reward) {
  int row = blockIdx.x*4 + (threadIdx.x >> 6);
  int lane = threadIdx.x & 63;
  if (row >= 3136) return;
  float M = -INFINITY, S = 0.f;
  for (int j = lane; j < 250; j += 64) {
    float m = pm[(size_t)row*250 + j], s = ps[(size_t)row*250 + j];
    float nm = fmaxf(M, m);
    S = S*expf(M - nm) + s*expf(m - nm);
    M = nm;
  }
  #pragma unroll
  for (int mk = 1; mk < 64; mk <<= 1) {
    float om = __shfl_xor(M, mk), os = __shfl_xor(S, mk);
    float nm = fmaxf(M, om);
    S = S*expf(M - nm) + os*expf(om - nm);
    M = nm;
  }
  if (lane == 0) reward[row] = ylogit[row] - (M + logf(S));
}

// ---------------- final losses ----------------
__global__ void final_kernel(const float* reward, const float* logp_s, const int* x_en, float* out) {
  int t = threadIdx.x;   // 64 threads, 1 wave
  float tl = 0.f, trl = 0.f;
  const float baseline = logf(1.0f / 32000.0f);
  if (t < 49) {
    float sr = 0.f, srl = 0.f; int cm = 0;
    for (int b = 0; b < 64; ++b) {
      int yv = x_en[b*50 + t + 1];
      if (yv != 1) {
        float rw = reward[b*49 + t];
        sr += rw;
        srl += logp_s[b*49 + t] * (rw - baseline);
        cm += 1;
      }
    }
    float cnt = fmaxf((float)cm, 1.f);
    tl = sr / cnt; trl = srl / cnt;
  }
  #pragma unroll
  for (int mk = 1; mk < 64; mk <<= 1) { tl += __shfl_xor(tl, mk); trl += __shfl_xor(trl, mk); }
  if (t == 0) { out[0] = -tl; out[1] = -trl; }
}

// ---------------- launch ----------------
extern "C" void kernel_launch(void* const* d_in, const int* in_sizes, int n_in,
                              void* d_out, int out_size, void* d_ws, size_t ws_size,
                              hipStream_t stream) {
  (void)in_sizes; (void)n_in; (void)out_size; (void)ws_size;
  const int*   x_de    = (const int*)d_in[0];
  const int*   x_en    = (const int*)d_in[1];
  const float* emb_de  = (const float*)d_in[2];
  const float* emb_en  = (const float*)d_in[3];
  const float* enc_Wih = (const float*)d_in[4];
  const float* enc_Whh = (const float*)d_in[5];
  const float* enc_bih = (const float*)d_in[6];
  const float* enc_bhh = (const float*)d_in[7];
  const float* dec_Wih = (const float*)d_in[8];
  const float* dec_Whh = (const float*)d_in[9];
  const float* dec_bih = (const float*)d_in[10];
  const float* dec_bhh = (const float*)d_in[11];
  const float* h2e_w   = (const float*)d_in[12];
  const float* h2e_b   = (const float*)d_in[13];
  const float* e2v_w   = (const float*)d_in[14];
  const float* e2v_b   = (const float*)d_in[15];
  float* out = (float*)d_out;

  char* ws = (char*)d_ws;
  size_t o = 0;
  auto alloc = [&](size_t bytes) { size_t rr = o; o += (bytes + 255) & ~(size_t)255; return rr; };
  int*   bar     = (int*)  (ws + alloc(2048));
  u16*   wih_p   = (u16*)  (ws + alloc(2ull*2048*320*2));
  u16*   whh_p   = (u16*)  (ws + alloc(2ull*2048*512*2));
  float* bsum    = (float*)(ws + alloc(2ull*2048*4));
  u16*   h2e_p   = (u16*)  (ws + alloc(512ull*1024*2));
  float* h2e_bp  = (float*)(ws + alloc(512ull*4));
  i8*    e2v_q   = (i8*)   (ws + alloc(32000ull*512));
  u16*   xg      = (u16*)  (ws + alloc(2ull*3200*2048*2));
  u16*   hglob   = (u16*)  (ws + alloc(2ull*2*64*512*2));
  float* h_out   = (float*)(ws + alloc(2ull*64*50*512*4));
  int*   samples = (int*)  (ws + alloc(3136ull*4));
  float* logp_s  = (float*)(ws + alloc(3136ull*4));
  float* ylogit  = (float*)(ws + alloc(3200ull*4));
  float* reward  = (float*)(ws + alloc(3136ull*4));
  i8*    e_q     = (i8*)   (ws + alloc(3200ull*512));
  float* pmb     = (float*)(ws + alloc(3200ull*250*4));
  float* psb     = (float*)(ws + alloc(3200ull*250*4));

  prep_all<<<2048, 256, 0, stream>>>(enc_Wih, enc_Whh, enc_bih, enc_bhh,
      dec_Wih, dec_Whh, dec_bih, dec_bhh, h2e_w, h2e_b, e2v_w,
      wih_p, whh_p, bsum, h2e_p, h2e_bp, e2v_q, hglob, bar);

  // xg = emb @ Wih^T + (bih+bhh), gate-interleaved packing, bf16 out
  gemm_k<0,0><<<dim3(25,16,2), 256, 0, stream>>>(emb_de, emb_en, x_de, x_en,
      wih_p, 320, 5, xg, bsum);

  lstm_kernel<<<32, 256, 0, stream>>>(xg, whh_p, hglob, h_out, bar);

  scores_sample_kernel<<<256, 256, 0, stream>>>(h_out, samples, logp_s);

  // e = tanh([dec_h, context] @ h2e^T + b) -> int8 (scale 127)
  gemm_k<1,1><<<dim3(25,4,1), 256, 0, stream>>>(h_out + 64ull*50*512, h_out, samples, nullptr,
      h2e_p, 1024, 16, (u16*)e_q, h2e_bp);

  // logits = e_q . w_q / (127*400) + b, int8 MFMA (A direct from L2), fused LSE partials
  gemm_e2v_i8<<<dim3(25,250,1), 256, 0, stream>>>(e_q, e2v_q, x_en, e2v_b, pmb, psb, ylogit);

  lse_reduce<<<784, 256, 0, stream>>>(pmb, psb, ylogit, reward);

  final_kernel<<<1, 64, 0, stream>>>(reward, logp_s, x_en, out);
}

// Round 17
// 683.384 us; speedup vs baseline: 1.0443x; 1.0443x over previous
//
#include <hip/hip_runtime.h>
#include <cstdint>

typedef short short8 __attribute__((ext_vector_type(8)));
typedef float f32x4 __attribute__((ext_vector_type(4)));
typedef int   i32x4 __attribute__((ext_vector_type(4)));
typedef uint32_t u32x4 __attribute__((ext_vector_type(4)));
typedef unsigned short u16;
typedef signed char i8;
typedef unsigned long long u64;

// ---------------- helpers ----------------
__device__ __forceinline__ u16 f2bf(float f) {
  union { float f; uint32_t u; } v; v.f = f;
  uint32_t u = v.u;
  uint32_t r = (u + 0x7fffu + ((u >> 16) & 1u)) >> 16;
  return (u16)r;
}
__device__ __forceinline__ float bf2f(u16 b) {
  union { uint32_t u; float f; } v; v.u = ((uint32_t)b) << 16; return v.f;
}
__device__ __forceinline__ i8 q8(float v, float s) {
  float x = rintf(v * s);
  x = fminf(fmaxf(x, -127.f), 127.f);
  return (i8)(int)x;
}
__device__ __forceinline__ float sigm(float x) { return 1.f / (1.f + expf(-x)); }
__device__ __forceinline__ float tanh_f(float x) { return 2.f / (1.f + expf(-2.f * x)) - 1.f; }

typedef const __attribute__((address_space(1))) uint32_t glb_u32;
typedef __attribute__((address_space(3))) uint32_t lds_u32;
__device__ __forceinline__ void glds16(const void* g, void* l) {
  __builtin_amdgcn_global_load_lds((glb_u32*)g, (lds_u32*)l, 16, 0, 0);
}

__device__ __forceinline__ void tfround(uint32_t& a, uint32_t& b, int r) {
  a += b; b = (b << r) | (b >> (32 - r)); b ^= a;
}
// exact JAX threefry2x32 (key 42 -> k0=0,k1=42)
__device__ __forceinline__ void threefry(uint32_t k0, uint32_t k1, uint32_t& x0, uint32_t& x1) {
  uint32_t k2 = k0 ^ k1 ^ 0x1BD11BDAu;
  x0 += k0; x1 += k1;
  tfround(x0,x1,13); tfround(x0,x1,15); tfround(x0,x1,26); tfround(x0,x1,6);
  x0 += k1; x1 += k2 + 1u;
  tfround(x0,x1,17); tfround(x0,x1,29); tfround(x0,x1,16); tfround(x0,x1,24);
  x0 += k2; x1 += k0 + 2u;
  tfround(x0,x1,13); tfround(x0,x1,15); tfround(x0,x1,26); tfround(x0,x1,6);
  x0 += k0; x1 += k1 + 3u;
  tfround(x0,x1,17); tfround(x0,x1,29); tfround(x0,x1,16); tfround(x0,x1,24);
  x0 += k1; x1 += k2 + 4u;
  tfround(x0,x1,13); tfround(x0,x1,15); tfround(x0,x1,26); tfround(x0,x1,6);
  x0 += k2; x1 += k0 + 5u;
}
__device__ __forceinline__ float gumbel_from_bits(uint32_t bits) {
  float f = __uint_as_float((bits >> 9) | 0x3f800000u) - 1.0f;
  const float tiny = 1.17549435e-38f;
  float u = fmaxf(f + tiny, tiny);
  return -logf(-logf(u));
}

// ---------------- prep: pack/convert weights (8-wide vectorized) ----------------
// Packed row index for Wih/bsum/xg columns: p = u*4 + g (gate-interleaved).
// e2v packed as int8, scale 400.
__global__ __launch_bounds__(256) void prep_all(
    const float* eWih, const float* eWhh, const float* ebih, const float* ebhh,
    const float* dWih, const float* dWhh, const float* dbih, const float* dbhh,
    const float* h2e_w, const float* h2e_b, const float* e2v_w,
    u16* wih_p, u16* whh_p, float* bsum, u16* h2e_p, float* h2e_bp,
    i8* e2v_q, u16* hglob, int* bar)
{
  const uint32_t GWIH = 2u*2048u*40u;      // 163840  (groups of 8 along k, 320/8)
  const uint32_t GWHH = 2u*2048u*64u;      // 262144
  const uint32_t GBS  = 512u;              // 2*2048/8
  const uint32_t GH2E = 512u*128u;         // 65536
  const uint32_t GH2EB= 64u;
  const uint32_t GE2V = 32000u*64u;        // 2048000
  const uint32_t GHG  = 16384u;            // 2*2*64*512/8
  const uint32_t GBAR = 512u;              // flag region (2 lstm x 256 ints)
  const uint32_t TOT  = GWIH+GWHH+GBS+GH2E+GH2EB+GE2V+GHG+GBAR;
  for (uint32_t i = blockIdx.x*256u + threadIdx.x; i < TOT; i += gridDim.x*256u) {
    uint32_t j = i;
    if (j < GWIH) { // [L][2048][320]: row p = u*4+g <- Wih[g*500+u][k0..k0+8]
      uint32_t L = j / (2048u*40u), rem = j % (2048u*40u);
      uint32_t p = rem / 40u, kg = rem % 40u;
      uint32_t u = p >> 2, g = p & 3u, k0 = kg*8u;
      short8 o = {0,0,0,0,0,0,0,0}; u16* op = (u16*)&o;
      if (u < 500u) {
        const float* src = (L ? dWih : eWih) + ((size_t)(g*500u+u))*300u + k0;
        if (k0 + 8u <= 300u) {
          float4 a = *(const float4*)src, b = *(const float4*)(src+4);
          op[0]=f2bf(a.x);op[1]=f2bf(a.y);op[2]=f2bf(a.z);op[3]=f2bf(a.w);
          op[4]=f2bf(b.x);op[5]=f2bf(b.y);op[6]=f2bf(b.z);op[7]=f2bf(b.w);
        } else {
          #pragma unroll
          for (int e = 0; e < 8; ++e) if (k0+e < 300u) op[e] = f2bf(src[e]);
        }
      }
      *(short8*)(wih_p + (size_t)j*8) = o; continue;
    }
    j -= GWIH;
    if (j < GWHH) { // [L][row][512], row = wg*128 + gate*32 + ul (16 wgs x 4 gate-waves)
      uint32_t L = j / (2048u*64u), rem = j % (2048u*64u);
      uint32_t row = rem >> 6, kg = rem & 63u, k0 = kg*8u;
      uint32_t wg = row >> 7, r2 = row & 127u, g = r2 >> 5, ul = r2 & 31u;
      uint32_t u = wg*32u + ul;
      short8 o = {0,0,0,0,0,0,0,0}; u16* op = (u16*)&o;
      if (u < 500u) {
        const float* src = (L ? dWhh : eWhh) + ((size_t)(g*500u+u))*500u + k0;
        if (k0 + 8u <= 500u) {
          float4 a = *(const float4*)src, b = *(const float4*)(src+4);
          op[0]=f2bf(a.x);op[1]=f2bf(a.y);op[2]=f2bf(a.z);op[3]=f2bf(a.w);
          op[4]=f2bf(b.x);op[5]=f2bf(b.y);op[6]=f2bf(b.z);op[7]=f2bf(b.w);
        } else {
          #pragma unroll
          for (int e = 0; e < 8; ++e) if (k0+e < 500u) op[e] = f2bf(src[e]);
        }
      }
      *(short8*)(whh_p + (size_t)j*8) = o; continue;
    }
    j -= GWHH;
    if (j < GBS) { // [L][2048] fp32, p = u*4+g
      uint32_t L = j >> 8, pg = j & 255u, p0 = pg*8u;
      float arr[8];
      #pragma unroll
      for (int e = 0; e < 8; ++e) {
        uint32_t p = p0 + e, u = p >> 2, g = p & 3u;
        arr[e] = (u < 500u) ? ((L?dbih:ebih)[g*500u+u] + (L?dbhh:ebhh)[g*500u+u]) : 0.f;
      }
      *(float4*)(bsum + (size_t)j*8) = *(float4*)arr;
      *(float4*)(bsum + (size_t)j*8 + 4) = *(float4*)(arr+4);
      continue;
    }
    j -= GBS;
    if (j < GH2E) { // [512][1024]: k<500 -> k ; 512..1011 -> k-12
      uint32_t n = j >> 7, kg = j & 127u, k0 = kg*8u;
      short8 o = {0,0,0,0,0,0,0,0}; u16* op = (u16*)&o;
      if (n < 500u) {
        const float* rowp = h2e_w + (size_t)n*1000u;
        if (k0 + 8u <= 500u) {
          float4 a = *(const float4*)(rowp+k0), b = *(const float4*)(rowp+k0+4);
          op[0]=f2bf(a.x);op[1]=f2bf(a.y);op[2]=f2bf(a.z);op[3]=f2bf(a.w);
          op[4]=f2bf(b.x);op[5]=f2bf(b.y);op[6]=f2bf(b.z);op[7]=f2bf(b.w);
        } else if (k0 >= 512u && k0 + 8u <= 1012u) {
          #pragma unroll
          for (int e = 0; e < 8; ++e) op[e] = f2bf(rowp[k0 + e - 12u]);
        } else {
          #pragma unroll
          for (int e = 0; e < 8; ++e) {
            uint32_t k = k0 + e; float v = 0.f;
            if (k < 500u) v = rowp[k];
            else if (k >= 512u && k < 1012u) v = rowp[k - 12u];
            op[e] = f2bf(v);
          }
        }
      }
      *(short8*)(h2e_p + (size_t)j*8) = o; continue;
    }
    j -= GH2E;
    if (j < GH2EB) {
      uint32_t k0 = j*8u;
      float arr[8];
      #pragma unroll
      for (int e = 0; e < 8; ++e) { uint32_t k = k0+e; arr[e] = (k < 500u) ? h2e_b[k] : 0.f; }
      *(float4*)(h2e_bp + (size_t)j*8) = *(float4*)arr;
      *(float4*)(h2e_bp + (size_t)j*8 + 4) = *(float4*)(arr+4);
      continue;
    }
    j -= GH2EB;
    if (j < GE2V) { // [32000][512] int8, w_q = rint(w*400)
      uint32_t n = j >> 6, kg = j & 63u, k0 = kg*8u;
      i8 o[8] = {0,0,0,0,0,0,0,0};
      const float* src = e2v_w + (size_t)n*500u + k0;
      if (k0 + 8u <= 500u) {
        float4 a = *(const float4*)src, b = *(const float4*)(src+4);
        o[0]=q8(a.x,400.f);o[1]=q8(a.y,400.f);o[2]=q8(a.z,400.f);o[3]=q8(a.w,400.f);
        o[4]=q8(b.x,400.f);o[5]=q8(b.y,400.f);o[6]=q8(b.z,400.f);o[7]=q8(b.w,400.f);
      } else {
        #pragma unroll
        for (int e = 0; e < 8; ++e) if (k0+e < 500u) o[e] = q8(src[e], 400.f);
      }
      *(u64*)(e2v_q + (size_t)j*8) = *(const u64*)o; continue;
    }
    j -= GE2V;
    if (j < GHG) { short8 z = {0,0,0,0,0,0,0,0}; *(short8*)(hglob + (size_t)j*8) = z; continue; }
    j -= GHG;
    if (j < GBAR) bar[j] = 0;
  }
}

// ---------------- fused dual-LSTM, 32 wgs x 256 thr, flag-vector barrier -------------
__global__ __launch_bounds__(256, 1) void lstm_kernel(
    const u16* xg /*[2][3200][2048] bf16 gate-interleaved (bias pre-added)*/, const u16* whh_p,
    u16* hglob /*[2buf][2lstm][64][512]*/, float* h_out /*[2][64][50][512]*/, int* bar)
{
  const int wg = blockIdx.x;     // 0..31
  const int lstm = wg >> 4;
  const int wgl = wg & 15;       // unit block (32 units)
  const int tid = threadIdx.x;
  const int wid = tid >> 6;      // wave = gate (i,f,g,o)
  const int lane = tid & 63;

  __shared__ u16 hbuf[64 * 512];        // 64KB, XOR-swizzled rows
  __shared__ float pre[4][64][34];      // stride 34 (==2 mod 8): 2-way max = free
  __shared__ u16 hsh[64 * 32];          // 4KB h-slice repack for 16B coherent stores

  // Whh fragments resident in registers: wave's 32 gate-rows x K=512
  short8 wf[2][16];
  {
    const u16* wbase = whh_p + ((size_t)lstm*2048 + wgl*128 + wid*32) * 512;
    #pragma unroll
    for (int nt = 0; nt < 2; ++nt)
      #pragma unroll
      for (int kk = 0; kk < 16; ++kk) {
        int row = nt*16 + (lane & 15);
        int k = kk*32 + (lane >> 4)*8;
        wf[nt][kk] = *(const short8*)(wbase + (size_t)row*512 + k);
      }
  }

  float c[8];
  #pragma unroll
  for (int q = 0; q < 8; ++q) c[q] = 0.f;

  int* flags = bar + lstm*256;      // 16 flags, 64B apart
  const int ug = wgl*32 + (tid & 31);
  const u16* xgl = xg + ((size_t)lstm*3200)*2048;

  // prefetch xg for t=0: one 8B load per batch (4 gates of unit ug, interleaved layout)
  float xr[4][8];
  #pragma unroll
  for (int q = 0; q < 8; ++q) {
    int b = q*8 + (tid >> 5);
    u64 w = *(const u64*)(xgl + ((size_t)(b*50 + 0))*2048 + ug*4);
    #pragma unroll
    for (int g = 0; g < 4; ++g) xr[g][q] = bf2f((u16)(w >> (g*16)));
  }

  #pragma unroll 1
  for (int t = 0; t < 50; ++t) {
    const int cur = t & 1;
    // ---- stage h[64][512]: 16 pipelined device-scope 16B loads -> swizzled LDS ----
    {
      u32x4 sv[16];
      const char* sbase = (const char*)(hglob + ((size_t)(cur*2 + lstm))*64*512);
      #pragma unroll
      for (int i = 0; i < 16; ++i) {
        const void* p = sbase + (size_t)(i*256 + tid)*16;
        asm volatile("global_load_dwordx4 %0, %1, off sc0 sc1" : "=v"(sv[i]) : "v"(p));
      }
      asm volatile("s_waitcnt vmcnt(0)" ::: "memory");
      __builtin_amdgcn_sched_barrier(0);
      #pragma unroll
      for (int i = 0; i < 16; ++i) {
        int chunk = i*256 + tid;               // 16B chunks, 64 per 1024B row
        int row = chunk >> 6, col16 = chunk & 63;
        int byte = row*1024 + ((col16*16) ^ ((row & 7) << 4));
        *(u32x4*)((char*)hbuf + byte) = sv[i];
      }
    }
    __syncthreads();

    // ---- MFMA: pre = h @ Whh_slice^T ----
    f32x4 zero = {0.f, 0.f, 0.f, 0.f};
    f32x4 acc[4][2];
    #pragma unroll
    for (int m = 0; m < 4; ++m) { acc[m][0] = zero; acc[m][1] = zero; }

    #pragma unroll
    for (int kk = 0; kk < 16; ++kk) {
      short8 af[4];
      #pragma unroll
      for (int m = 0; m < 4; ++m) {
        int row = m*16 + (lane & 15);
        int byte = row*1024 + ((kk*64 + (lane >> 4)*16) ^ ((row & 7) << 4));
        af[m] = *(const short8*)((const char*)hbuf + byte);
      }
      #pragma unroll
      for (int m = 0; m < 4; ++m) {
        acc[m][0] = __builtin_amdgcn_mfma_f32_16x16x32_bf16(af[m], wf[0][kk], acc[m][0], 0, 0, 0);
        acc[m][1] = __builtin_amdgcn_mfma_f32_16x16x32_bf16(af[m], wf[1][kk], acc[m][1], 0, 0, 0);
      }
    }

    #pragma unroll
    for (int m = 0; m < 4; ++m)
      #pragma unroll
      for (int nt = 0; nt < 2; ++nt)
        #pragma unroll
        for (int jj = 0; jj < 4; ++jj) {
          int row = m*16 + (lane >> 4)*4 + jj;   // batch
          int col = nt*16 + (lane & 15);         // unit local
          pre[wid][row][col] = acc[m][nt][jj];
        }
    __syncthreads();

    // ---- gates epilogue (xg in registers); h_out deferred off the critical path ----
    float hq[8];
    #pragma unroll
    for (int q = 0; q < 8; ++q) {
      int b = q*8 + (tid >> 5);
      int ul = tid & 31;
      float pi = pre[0][b][ul] + xr[0][q];
      float pf = pre[1][b][ul] + xr[1][q];
      float pg = pre[2][b][ul] + xr[2][q];
      float po = pre[3][b][ul] + xr[3][q];
      c[q] = sigm(pf)*c[q] + sigm(pi)*tanh_f(pg);
      float h = sigm(po)*tanh_f(c[q]);
      if (ug >= 500) h = 0.f;
      hq[q] = h;
      hsh[b*32 + ul] = f2bf(h);
    }
    if (t == 49) {
      #pragma unroll
      for (int q = 0; q < 8; ++q) {
        int b = q*8 + (tid >> 5);
        h_out[(((size_t)(lstm*64 + b))*50 + t)*512 + ug] = hq[q];
      }
      break;                          // no exchange needed after last step
    }
    __syncthreads();   // hsh complete

    // ---- cooperative device-scope store of this wg's h slice (16B/thread) ----
    {
      u16* hdst = hglob + ((size_t)((cur^1)*2 + lstm))*64*512;
      int b2 = tid >> 2, c8 = (tid & 3)*8;
      u32x4 w = *(const u32x4*)(hsh + b2*32 + c8);
      void* dp = hdst + (size_t)b2*512 + wgl*32 + c8;
      asm volatile("global_store_dwordx4 %0, %1, off sc0 sc1" :: "v"(dp), "v"(w) : "memory");
    }
    asm volatile("s_waitcnt vmcnt(0)" ::: "memory");   // drains ONLY hglob stores now
    __syncthreads();                                   // ALL waves drained

    if (tid == 0)
      __hip_atomic_store(flags + wgl*16, t+1, __ATOMIC_RELAXED, __HIP_MEMORY_SCOPE_AGENT);

    // overlap region (flies under the flag poll): h_out writes + xg prefetch
    #pragma unroll
    for (int q = 0; q < 8; ++q) {
      int b = q*8 + (tid >> 5);
      h_out[(((size_t)(lstm*64 + b))*50 + t)*512 + ug] = hq[q];
    }
    {
      const int tn = t + 1;
      #pragma unroll
      for (int q = 0; q < 8; ++q) {
        int b = q*8 + (tid >> 5);
        u64 w = *(const u64*)(xgl + ((size_t)(b*50 + tn))*2048 + ug*4);
        #pragma unroll
        for (int g = 0; g < 4; ++g) xr[g][q] = bf2f((u16)(w >> (g*16)));
      }
    }

    // ---- flag-vector poll: wave 0, lane j watches flag j (4x coverage) ----
    if (wid == 0) {
      int fj = (lane & 15) * 16;
      while (true) {
        int v = __hip_atomic_load(flags + fj, __ATOMIC_RELAXED, __HIP_MEMORY_SCOPE_AGENT);
        if (__ballot(v >= t + 1) == ~0ull) break;
      }
    }
    __syncthreads();
  }
}

// -------- scores+sample fused: per-b enc staged in LDS, inline exact sampling --------
__global__ __launch_bounds__(256) void scores_sample_kernel(const float* h_out,
                                                            int* samples, float* logp_s) {
  int b = blockIdx.x >> 2, tq = blockIdx.x & 3;
  int tid = threadIdx.x, wid = tid >> 6, lane = tid & 63;
  __shared__ float enc[50*512];   // 100KB
  const float* ebase = h_out + ((size_t)b*50)*512;
  for (int i = tid*4; i < 50*512; i += 256*4)
    *(float4*)(enc + i) = *(const float4*)(ebase + i);
  __syncthreads();
  const int t0 = tq*13;
  const int cnt = (tq == 3) ? 10 : 13;
  for (int tl = wid; tl < cnt; tl += 4) {
    int t = t0 + tl;
    const float* drow = h_out + ((size_t)((64 + b)*50 + t))*512;
    float d[8];
    #pragma unroll
    for (int j = 0; j < 8; ++j) d[j] = drow[lane + j*64];
    float sc = -INFINITY;
    for (int s = 0; s < 50; ++s) {
      float p = 0.f;
      #pragma unroll
      for (int j = 0; j < 8; ++j) p += enc[s*512 + lane + j*64] * d[j];
      #pragma unroll
      for (int mk = 32; mk; mk >>= 1) p += __shfl_xor(p, mk);
      if (lane == s) sc = p;            // full-reduced value lives on every lane
    }
    // ---- inline exact jax.random.categorical(key(42)) on this wave ----
    const int pidx = b*49 + t;
    float val = -INFINITY;
    if (lane < 50) {
      uint32_t i = (uint32_t)(pidx*50 + lane);
      uint32_t x0, x1; int sel;
      if (i < 78400u) { x0 = i; x1 = i + 78400u; sel = 0; }
      else            { x0 = i - 78400u; x1 = i; sel = 1; }
      threefry(0u, 42u, x0, x1);
      val = sc + gumbel_from_bits(sel ? x1 : x0);
    }
    int idx = lane; float v = val;
    #pragma unroll
    for (int mk = 1; mk < 64; mk <<= 1) {
      float ov = __shfl_xor(v, mk);
      int oi = __shfl_xor(idx, mk);
      if (ov > v || (ov == v && oi < idx)) { v = ov; idx = oi; }
    }
    float m = sc;
    #pragma unroll
    for (int mk = 1; mk < 64; mk <<= 1) m = fmaxf(m, __shfl_xor(m, mk));
    float e = (lane < 50) ? expf(sc - m) : 0.f;
    #pragma unroll
    for (int mk = 1; mk < 64; mk <<= 1) e += __shfl_xor(e, mk);
    float lse = m + logf(e);
    float scs = __shfl(sc, idx);
    if (lane == 0) { samples[pidx] = idx; logp_s[pidx] = scs - lse; }
  }
}

// ---------------- generic 128x128x64 MFMA GEMM (reg-staged A/B) ----------
// AMODE: 0 emb-gather(fp32->bf16), 1 feat-gather(fp32->bf16)
// EPI:   0 bf16 store + bias (xg, ldc 2048, z-offset), 1 tanh(acc+bias)->int8 (ldc 512)
template <int AMODE, int EPI>
__global__ __launch_bounds__(256) void gemm_k(
    const float* Af32a, const float* Af32b, const int* gia, const int* gib,
    const u16* Bp, int ldkB, int KT,
    u16* Cbf, const float* bias)
{
  const int Mb = blockIdx.x, Nb = blockIdx.y, zb = blockIdx.z;
  const int tid = threadIdx.x;
  const int wid = tid >> 6, lane = tid & 63;
  const int wr = wid >> 1, wc = wid & 1;

  __shared__ u16 As[2*128*64];
  __shared__ u16 Bs[2*128*64];

  f32x4 zero = {0.f,0.f,0.f,0.f};
  f32x4 acc[4][4];
  #pragma unroll
  for (int m = 0; m < 4; ++m)
    #pragma unroll
    for (int n = 0; n < 4; ++n) acc[m][n] = zero;

  auto MFMA_STEP = [&](int buf) {
    #pragma unroll
    for (int kk2 = 0; kk2 < 2; ++kk2) {
      short8 a[4], b[4];
      #pragma unroll
      for (int m = 0; m < 4; ++m) {
        int row = wr*64 + m*16 + (lane & 15);
        int byte = buf*16384 + row*128 + ((kk2*64 + (lane >> 4)*16) ^ ((row & 7) << 4));
        a[m] = *(const short8*)((const char*)As + byte);
      }
      #pragma unroll
      for (int n = 0; n < 4; ++n) {
        int row = wc*64 + n*16 + (lane & 15);
        int byte = buf*16384 + row*128 + ((kk2*64 + (lane >> 4)*16) ^ ((row & 7) << 4));
        b[n] = *(const short8*)((const char*)Bs + byte);
      }
      #pragma unroll
      for (int m = 0; m < 4; ++m)
        #pragma unroll
        for (int n = 0; n < 4; ++n)
          acc[m][n] = __builtin_amdgcn_mfma_f32_16x16x32_bf16(a[m], b[n], acc[m][n], 0, 0, 0);
    }
  };

  const int r = tid >> 1;
  const int koff = (tid & 1)*32;
  const int growA = Mb*128 + r;
  const int growB = Nb*128 + r;

  const float* emb = nullptr; const int* ids = nullptr;
  int fb = 0, ft = 0, fsmp = 0; bool fvalid = true;
  if constexpr (AMODE == 0) {
    emb = zb ? Af32b : Af32a;
    ids = zb ? gib : gia;
  } else {
    fvalid = growA < 3136;
    fb = growA / 49; ft = growA - fb*49;
    fsmp = fvalid ? gia[growA] : 0;
  }

  short8 av8[4], bv8[4];
  auto FETCH = [&](int it) {
    const int k0 = it*64 + koff;
    u16* avp = (u16*)av8;
    if constexpr (AMODE == 0) {
      const float* srow = emb + (size_t)ids[growA]*300;
      #pragma unroll
      for (int j = 0; j < 8; ++j) {
        int k = k0 + j*4;
        float4 v = make_float4(0.f,0.f,0.f,0.f);
        if (k + 4 <= 300) v = *(const float4*)(srow + k);
        avp[j*4+0]=f2bf(v.x); avp[j*4+1]=f2bf(v.y); avp[j*4+2]=f2bf(v.z); avp[j*4+3]=f2bf(v.w);
      }
    } else {
      #pragma unroll
      for (int j = 0; j < 8; ++j) {
        int k = k0 + j*4;
        float4 v = make_float4(0.f,0.f,0.f,0.f);
        if (fvalid) {
          if (k + 4 <= 500) v = *(const float4*)(Af32a + ((size_t)(fb*50 + ft))*512 + k);
          else if (k >= 512 && k + 4 <= 1012) v = *(const float4*)(Af32b + ((size_t)(fb*50 + fsmp))*512 + (k - 512));
        }
        avp[j*4+0]=f2bf(v.x); avp[j*4+1]=f2bf(v.y); avp[j*4+2]=f2bf(v.z); avp[j*4+3]=f2bf(v.w);
      }
    }
    #pragma unroll
    for (int j = 0; j < 4; ++j)
      bv8[j] = *(const short8*)(Bp + (size_t)growB*ldkB + k0 + j*8);
  };
  auto STORE_LDS = [&](int buf) {
    #pragma unroll
    for (int j = 0; j < 4; ++j) {
      int byte = buf*16384 + r*128 + ((koff*2 + j*16) ^ ((r & 7) << 4));
      *(short8*)((char*)As + byte) = av8[j];
      *(short8*)((char*)Bs + byte) = bv8[j];
    }
  };

  FETCH(0);
  STORE_LDS(0);
  __syncthreads();
  for (int it = 0; it < KT; ++it) {
    const int cur = it & 1;
    if (it + 1 < KT) FETCH(it + 1);
    MFMA_STEP(cur);
    __syncthreads();
    if (it + 1 < KT) {
      STORE_LDS(cur ^ 1);
      __syncthreads();
    }
  }

  if constexpr (EPI == 0) {
    u16* C = Cbf + (size_t)zb*3200*2048;
    const float* bs = bias + (size_t)zb*2048;
    #pragma unroll
    for (int m = 0; m < 4; ++m)
      #pragma unroll
      for (int n = 0; n < 4; ++n)
        #pragma unroll
        for (int jj = 0; jj < 4; ++jj) {
          int row = Mb*128 + wr*64 + m*16 + (lane >> 4)*4 + jj;
          int col = Nb*128 + wc*64 + n*16 + (lane & 15);
          C[(size_t)row*2048 + col] = f2bf(acc[m][n][jj] + bs[col]);
        }
  } else {
    i8* Cq = (i8*)Cbf;
    #pragma unroll
    for (int m = 0; m < 4; ++m)
      #pragma unroll
      for (int n = 0; n < 4; ++n)
        #pragma unroll
        for (int jj = 0; jj < 4; ++jj) {
          int row = Mb*128 + wr*64 + m*16 + (lane >> 4)*4 + jj;
          int col = Nb*128 + wc*64 + n*16 + (lane & 15);
          float e = tanh_f(acc[m][n][jj] + bias[col]);
          Cq[(size_t)row*512 + col] = q8(e, 127.f);
        }
  }
}

// ------- e2v int8 GEMM: 128x128, K=512 via 8 x mfma_i32_16x16x64_i8 ------------------
// 3-buffer counted-vmcnt glds pipeline, 50KB LDS -> 3 wgs/CU, XCD-swizzled tiles.
// logits = (e_q . w_q) / (127*400) + bias; fused online row-LSE partials + y-logit.
__global__ __launch_bounds__(256) void gemm_e2v_i8(
    const i8* e_q /*[3200][512]*/, const i8* w_q /*[32000][512]*/,
    const int* x_en, const float* bias,
    float* pm, float* ps, float* ylogit)
{
  int bid = blockIdx.y*gridDim.x + blockIdx.x;
  const int NBLK = 25*250, q = NBLK/8, r = NBLK%8;   // 781, 2
  int xcd = bid & 7, idx = bid >> 3;
  int wgid = (xcd < r ? xcd*(q+1) : r*(q+1) + (xcd-r)*q) + idx;
  int Mb = wgid % 25, Nb = wgid / 25;
  const int tid = threadIdx.x;
  const int wid = tid >> 6, lane = tid & 63;
  const int wr = wid >> 1, wc = wid & 1;

  __shared__ i8 As[3*128*64];       // 3 x 8KB (64B rows = K=64 i8)
  __shared__ i8 Bs[3*128*64];
  __shared__ float part[128][2][2];

  i32x4 acc[4][4];
  #pragma unroll
  for (int m = 0; m < 4; ++m)
    #pragma unroll
    for (int n = 0; n < 4; ++n) { i32x4 z = {0,0,0,0}; acc[m][n] = z; }

  auto ISSUE = [&](int it, int buf) {
    #pragma unroll
    for (int i = 0; i < 2; ++i) {
      int chunk = i*256 + tid;        // 512 chunks/tile, 4 x 16B per 64B row
      int row = chunk >> 2, c = chunk & 3;
      int cg = c ^ ((row >> 1) & 3);  // source pre-swizzle == read swizzle
      const i8* sa = e_q + (size_t)(Mb*128 + row)*512 + it*64 + cg*16;
      const i8* sb = w_q + (size_t)(Nb*128 + row)*512 + it*64 + cg*16;
      char* da = (char*)As + buf*8192 + i*4096 + wid*1024;   // wave-uniform base
      char* db = (char*)Bs + buf*8192 + i*4096 + wid*1024;
      glds16(sa, da);
      glds16(sb, db);
    }
  };

  auto MFMA_STEP = [&](int buf) {
    i32x4 a[4], b[4];
    #pragma unroll
    for (int m = 0; m < 4; ++m) {
      int row = wr*64 + m*16 + (lane & 15);
      int byte = buf*8192 + row*64 + (((lane >> 4)*16) ^ (((row >> 1) & 3) << 4));
      a[m] = *(const i32x4*)((const char*)As + byte);
    }
    #pragma unroll
    for (int n = 0; n < 4; ++n) {
      int row = wc*64 + n*16 + (lane & 15);
      int byte = buf*8192 + row*64 + (((lane >> 4)*16) ^ (((row >> 1) & 3) << 4));
      b[n] = *(const i32x4*)((const char*)Bs + byte);
    }
    #pragma unroll
    for (int m = 0; m < 4; ++m)
      #pragma unroll
      for (int n = 0; n < 4; ++n)
        acc[m][n] = __builtin_amdgcn_mfma_i32_16x16x64_i8(a[m], b[n], acc[m][n], 0, 0, 0);
  };

  // 3-buffer, counted-vmcnt pipeline over KT=8 K-steps
  ISSUE(0, 0);
  ISSUE(1, 1);
  asm volatile("s_waitcnt vmcnt(4)" ::: "memory");   // tile 0 landed (tile 1 in flight)
  __syncthreads();
  for (int it = 0; it < 8; ++it) {
    if (it + 2 < 8) ISSUE(it + 2, (it + 2) % 3);
    MFMA_STEP(it % 3);
    if (it + 1 < 8) {
      if (it + 2 < 8) asm volatile("s_waitcnt vmcnt(4)" ::: "memory");
      else            asm volatile("s_waitcnt vmcnt(0)" ::: "memory");
      __syncthreads();
    }
  }

  const float DEQ = 1.f / (127.f * 400.f);
  float bias4[4];
  #pragma unroll
  for (int n = 0; n < 4; ++n) bias4[n] = bias[Nb*128 + wc*64 + n*16 + (lane & 15)];
  #pragma unroll
  for (int m = 0; m < 4; ++m)
    #pragma unroll
    for (int jj = 0; jj < 4; ++jj) {
      int trow = wr*64 + m*16 + (lane >> 4)*4 + jj;
      int grow = Mb*128 + trow;
      float x0 = (float)acc[m][0][jj]*DEQ + bias4[0];
      float x1 = (float)acc[m][1][jj]*DEQ + bias4[1];
      float x2 = (float)acc[m][2][jj]*DEQ + bias4[2];
      float x3 = (float)acc[m][3][jj]*DEQ + bias4[3];
      float mx = fmaxf(fmaxf(x0,x1), fmaxf(x2,x3));
      #pragma unroll
      for (int mk = 1; mk < 16; mk <<= 1) mx = fmaxf(mx, __shfl_xor(mx, mk));
      float sm = expf(x0-mx) + expf(x1-mx) + expf(x2-mx) + expf(x3-mx);
      #pragma unroll
      for (int mk = 1; mk < 16; mk <<= 1) sm += __shfl_xor(sm, mk);
      if (grow < 3136) {
        int b = grow / 49, tt = grow - b*49;
        int yv = x_en[b*50 + tt + 1];
        int cb = yv - (Nb*128 + wc*64);
        if (cb == 0*16 + (lane & 15)) ylogit[grow] = x0;
        if (cb == 1*16 + (lane & 15)) ylogit[grow] = x1;
        if (cb == 2*16 + (lane & 15)) ylogit[grow] = x2;
        if (cb == 3*16 + (lane & 15)) ylogit[grow] = x3;
      }
      if ((lane & 15) == 0) { part[trow][wc][0] = mx; part[trow][wc][1] = sm; }
    }
  __syncthreads();
  if (tid < 128) {
    int grow = Mb*128 + tid;
    if (grow < 3136) {
      float m0 = part[tid][0][0], s0 = part[tid][0][1];
      float m1 = part[tid][1][0], s1 = part[tid][1][1];
      float M = fmaxf(m0, m1);
      float S = s0*expf(m0 - M) + s1*expf(m1 - M);
      pm[(size_t)grow*250 + Nb] = M;
      ps[(size_t)grow*250 + Nb] = S;
    }
  }
}

// ---------------- combine LSE partials -> reward (wave-parallel) ----------------
__global__ __launch_bounds__(256) void lse_reduce(const float* pm, const float* ps,
                                                  const float* ylogit, float* reward) {
  int row = blockIdx.x*4 + (threadIdx.x >> 6);
  int lane = threadIdx.x & 63;
  if (row >= 3136) return;
  float M = -INFINITY, S = 0.f;
  for (int j = lane; j < 250; j += 64) {
    float m = pm[(size_t)row*250 + j], s = ps[(size_t)row*250 + j];
    float nm = fmaxf(M, m);
    S = S*expf(M - nm) + s*expf(m - nm);
    M = nm;
  }
  #pragma unroll
  for (int mk = 1; mk < 64; mk <<= 1) {
    float om = __shfl_xor(M, mk), os = __shfl_xor(S, mk);
    float nm = fmaxf(M, om);
    S = S*expf(M - nm) + os*expf(om - nm);
    M = nm;
  }
  if (lane == 0) reward[row] = ylogit[row] - (M + logf(S));
}

// ---------------- final losses ----------------
__global__ void final_kernel(const float* reward, const float* logp_s, const int* x_en, float* out) {
  int t = threadIdx.x;   // 64 threads, 1 wave
  float tl = 0.f, trl = 0.f;
  const float baseline = logf(1.0f / 32000.0f);
  if (t < 49) {
    float sr = 0.f, srl = 0.f; int cm = 0;
    for (int b = 0; b < 64; ++b) {
      int yv = x_en[b*50 + t + 1];
      if (yv != 1) {
        float rw = reward[b*49 + t];
        sr += rw;
        srl += logp_s[b*49 + t] * (rw - baseline);
        cm += 1;
      }
    }
    float cnt = fmaxf((float)cm, 1.f);
    tl = sr / cnt; trl = srl / cnt;
  }
  #pragma unroll
  for (int mk = 1; mk < 64; mk <<= 1) { tl += __shfl_xor(tl, mk); trl += __shfl_xor(trl, mk); }
  if (t == 0) { out[0] = -tl; out[1] = -trl; }
}

// ---------------- launch ----------------
extern "C" void kernel_launch(void* const* d_in, const int* in_sizes, int n_in,
                              void* d_out, int out_size, void* d_ws, size_t ws_size,
                              hipStream_t stream) {
  (void)in_sizes; (void)n_in; (void)out_size; (void)ws_size;
  const int*   x_de    = (const int*)d_in[0];
  const int*   x_en    = (const int*)d_in[1];
  const float* emb_de  = (const float*)d_in[2];
  const float* emb_en  = (const float*)d_in[3];
  const float* enc_Wih = (const float*)d_in[4];
  const float* enc_Whh = (const float*)d_in[5];
  const float* enc_bih = (const float*)d_in[6];
  const float* enc_bhh = (const float*)d_in[7];
  const float* dec_Wih = (const float*)d_in[8];
  const float* dec_Whh = (const float*)d_in[9];
  const float* dec_bih = (const float*)d_in[10];
  const float* dec_bhh = (const float*)d_in[11];
  const float* h2e_w   = (const float*)d_in[12];
  const float* h2e_b   = (const float*)d_in[13];
  const float* e2v_w   = (const float*)d_in[14];
  const float* e2v_b   = (const float*)d_in[15];
  float* out = (float*)d_out;

  char* ws = (char*)d_ws;
  size_t o = 0;
  auto alloc = [&](size_t bytes) { size_t rr = o; o += (bytes + 255) & ~(size_t)255; return rr; };
  int*   bar     = (int*)  (ws + alloc(2048));
  u16*   wih_p   = (u16*)  (ws + alloc(2ull*2048*320*2));
  u16*   whh_p   = (u16*)  (ws + alloc(2ull*2048*512*2));
  float* bsum    = (float*)(ws + alloc(2ull*2048*4));
  u16*   h2e_p   = (u16*)  (ws + alloc(512ull*1024*2));
  float* h2e_bp  = (float*)(ws + alloc(512ull*4));
  i8*    e2v_q   = (i8*)   (ws + alloc(32000ull*512));
  u16*   xg      = (u16*)  (ws + alloc(2ull*3200*2048*2));
  u16*   hglob   = (u16*)  (ws + alloc(2ull*2*64*512*2));
  float* h_out   = (float*)(ws + alloc(2ull*64*50*512*4));
  int*   samples = (int*)  (ws + alloc(3136ull*4));
  float* logp_s  = (float*)(ws + alloc(3136ull*4));
  float* ylogit  = (float*)(ws + alloc(3200ull*4));
  float* reward  = (float*)(ws + alloc(3136ull*4));
  i8*    e_q     = (i8*)   (ws + alloc(3200ull*512));
  float* pmb     = (float*)(ws + alloc(3200ull*250*4));
  float* psb     = (float*)(ws + alloc(3200ull*250*4));

  prep_all<<<2048, 256, 0, stream>>>(enc_Wih, enc_Whh, enc_bih, enc_bhh,
      dec_Wih, dec_Whh, dec_bih, dec_bhh, h2e_w, h2e_b, e2v_w,
      wih_p, whh_p, bsum, h2e_p, h2e_bp, e2v_q, hglob, bar);

  // xg = emb @ Wih^T + (bih+bhh), gate-interleaved packing, bf16 out
  gemm_k<0,0><<<dim3(25,16,2), 256, 0, stream>>>(emb_de, emb_en, x_de, x_en,
      wih_p, 320, 5, xg, bsum);

  lstm_kernel<<<32, 256, 0, stream>>>(xg, whh_p, hglob, h_out, bar);

  scores_sample_kernel<<<256, 256, 0, stream>>>(h_out, samples, logp_s);

  // e = tanh([dec_h, context] @ h2e^T + b) -> int8 (scale 127)
  gemm_k<1,1><<<dim3(25,4,1), 256, 0, stream>>>(h_out + 64ull*50*512, h_out, samples, nullptr,
      h2e_p, 1024, 16, (u16*)e_q, h2e_bp);

  // logits = e_q . w_q / (127*400) + b, int8 MFMA, fused LSE partials
  gemm_e2v_i8<<<dim3(25,250,1), 256, 0, stream>>>(e_q, e2v_q, x_en, e2v_b, pmb, psb, ylogit);

  lse_reduce<<<784, 256, 0, stream>>>(pmb, psb, ylogit, reward);

  final_kernel<<<1, 64, 0, stream>>>(reward, logp_s, x_en, out);
}